// Round 7
// baseline (150.977 us; speedup 1.0000x reference)
//
#include <hip/hip_runtime.h>
#include <cstdint>
#include <cmath>

#define NB 8192
#define ND 128
#define CAP 64
#define NEG_INF (-__builtin_inff())

typedef __attribute__((ext_vector_type(8))) __bf16 bf16x8;
typedef __attribute__((ext_vector_type(2))) __bf16 bf16x2;
typedef __attribute__((ext_vector_type(4))) float f32x4;

// Insert v into ascending top-K list (identity when v <= t[0]).
__device__ __forceinline__ void insert10(float t[10], float v) {
#pragma unroll
  for (int j = 0; j < 9; ++j) t[j] = __builtin_amdgcn_fmed3f(t[j], t[j + 1], v);
  t[9] = fmaxf(t[9], v);
}
__device__ __forceinline__ void insert11(float t[11], float v) {
#pragma unroll
  for (int j = 0; j < 10; ++j) t[j] = __builtin_amdgcn_fmed3f(t[j], t[j + 1], v);
  t[10] = fmaxf(t[10], v);
}

// ---------------------------------------------------------------------------
// Row loss via column-10-only soft sort (P row-stochastic => p_neg = 1-p_pos,
// clips no-ops, both BCEs identical). Verified exact in R3/R5/R6 (absmax 0).
// ---------------------------------------------------------------------------
__device__ float row_loss(float x[11]) {
  float al[55];
#pragma unroll
  for (int layer = 0; layer < 11; ++layer) {
#pragma unroll
    for (int p = 0; p < 5; ++p) {
      int ii = (layer & 1) + 2 * p;
      float av = x[ii], bv = x[ii + 1];
      float a = atanf(bv - av) * 0.3183098861837907f + 0.5f;
      al[layer * 5 + p] = a;
      float be = 1.f - a;
      x[ii] = a * av + be * bv;
      x[ii + 1] = be * av + a * bv;
    }
  }
  float v[11];
#pragma unroll
  for (int i = 0; i < 11; ++i) v[i] = 0.f;
  v[10] = 1.f;
#pragma unroll
  for (int layer = 10; layer >= 0; --layer) {
#pragma unroll
    for (int p = 0; p < 5; ++p) {
      int ii = (layer & 1) + 2 * p;
      float a = al[layer * 5 + p];
      float be = 1.f - a;
      float va = v[ii], vb = v[ii + 1];
      v[ii] = a * va + be * vb;
      v[ii + 1] = be * va + a * vb;
    }
  }
  float C = fmaxf(logf(v[10]), -100.f);
#pragma unroll
  for (int i = 0; i < 10; ++i) C += fmaxf(logf(1.f - v[i]), -100.f);
  return C;
}

// ---------------------------------------------------------------------------
// Kernel 1: row-normalize -> bf16 + fp32 pos_sims; block 0 zeroes d_out.
// ---------------------------------------------------------------------------
__global__ __launch_bounds__(256, 4) void knorm(const float* __restrict__ aug1,
                                                const float* __restrict__ aug2,
                                                __bf16* __restrict__ an,
                                                float* __restrict__ pos,
                                                float* __restrict__ out) {
  if (blockIdx.x == 0 && threadIdx.x == 0) out[0] = 0.f;
  int wid = threadIdx.x >> 6;
  int l = threadIdx.x & 63;
  int row = blockIdx.x * 4 + wid;
  const float2* a1 = (const float2*)(aug1) + (size_t)row * 64;
  const float2* a2 = (const float2*)(aug2) + (size_t)row * 64;
  float2 v1 = a1[l], v2 = a2[l];
  float ss1 = v1.x * v1.x + v1.y * v1.y;
  float ss2 = v2.x * v2.x + v2.y * v2.y;
  float dp = v1.x * v2.x + v1.y * v2.y;
#pragma unroll
  for (int off = 1; off < 64; off <<= 1) {
    ss1 += __shfl_xor(ss1, off);
    ss2 += __shfl_xor(ss2, off);
    dp += __shfl_xor(dp, off);
  }
  float inv1 = 1.0f / fmaxf(sqrtf(ss1), 1e-8f);
  float inv2 = 1.0f / fmaxf(sqrtf(ss2), 1e-8f);
  bf16x2 o1, o2;
  o1[0] = (__bf16)(v1.x * inv1);
  o1[1] = (__bf16)(v1.y * inv1);
  o2[0] = (__bf16)(v2.x * inv2);
  o2[1] = (__bf16)(v2.y * inv2);
  ((bf16x2*)(an))[(size_t)row * 64 + l] = o1;
  ((bf16x2*)(an + (size_t)NB * ND))[(size_t)row * 64 + l] = o2;
  if (l == 0) pos[row] = dp * inv1 * inv2;
}

// Unconditional (no diag mask) survivor append to per-row LDS buffers.
__device__ __forceinline__ void consume4(const f32x4* acc, float (*cand)[CAP],
                                         int* lcnt, float tau, int c) {
#pragma unroll
  for (int rb = 0; rb < 4; ++rb) {
    int rl = rb * 16 + c;
#pragma unroll
    for (int r = 0; r < 4; ++r) {
      float v = acc[rb][r];
      if (v > tau) {
        int s = atomicAdd(&lcnt[rl], 1);
        if (s < CAP) cand[rl][s] = v;
      }
    }
  }
}

// ---------------------------------------------------------------------------
// Kernel 2: fused Gram + threshold filter. QUARTER columns per block:
// grid = (128 rowg x 4 qtr, 2 dir) = 1024 blocks = 4 blocks/CU = 16 waves/CU
// (R6's 512 blocks = 8 waves/CU was latency-bound with both pipes ~85% idle).
// Diagonal handled in epilogue (drop-max in the diag-containing quarter).
// ---------------------------------------------------------------------------
__global__ __launch_bounds__(256, 4) void kgram(const __bf16* __restrict__ an_all,
                                                float* __restrict__ tk,
                                                int* __restrict__ cnth,
                                                float* __restrict__ taug) {
  int dir = blockIdx.y;
  int rowg = blockIdx.x >> 2;
  int qtr = blockIdx.x & 3;
  const bf16x8* an8 = (const bf16x8*)(an_all + (size_t)dir * NB * ND);
  int w = threadIdx.x >> 6;
  int l = threadIdx.x & 63;
  int q = l >> 4;
  int c = l & 15;
  int row_base = rowg * 64;
  const int col0 = qtr * 2048;

  __shared__ float cand[64][CAP];
  __shared__ int lcnt[64];
  __shared__ float sred[2][4];
  if (threadIdx.x < 64) lcnt[threadIdx.x] = 0;

  // Row fragments (B-operand), resident all kernel (compiler -> AGPRs).
  bf16x8 brow[4][4];
#pragma unroll
  for (int rb = 0; rb < 4; ++rb)
#pragma unroll
    for (int kc = 0; kc < 4; ++kc)
      brow[rb][kc] = an8[(size_t)(row_base + rb * 16 + c) * 16 + kc * 4 + q];

  const bf16x8* pf0 = an8 + ((size_t)(col0 + w * 16 + c) * 16 + q);
  bf16x8 a[4], a2[4];
  const f32x4 zz = {0.f, 0.f, 0.f, 0.f};
  f32x4 accA[4], accB[4];

  auto loadA = [&](int t) {  // tile t -> a (t wraps mod 32 harmlessly)
    const bf16x8* p = pf0 + (size_t)(t & 31) * 1024;
#pragma unroll
    for (int kc = 0; kc < 4; ++kc) a[kc] = p[kc * 4];
  };
  auto loadA2 = [&](int t) {  // tile t -> a2
    const bf16x8* p = pf0 + (size_t)(t & 31) * 1024;
#pragma unroll
    for (int kc = 0; kc < 4; ++kc) a2[kc] = p[kc * 4];
  };
  auto mfma_tile = [&](f32x4* A, const bf16x8* src) {
#pragma unroll
    for (int rb = 0; rb < 4; ++rb)
      A[rb] = __builtin_amdgcn_mfma_f32_16x16x32_bf16(src[0], brow[rb][0], zz, 0, 0, 0);
#pragma unroll
    for (int kc = 1; kc < 4; ++kc)
#pragma unroll
      for (int rb = 0; rb < 4; ++rb)
        A[rb] = __builtin_amdgcn_mfma_f32_16x16x32_bf16(src[kc], brow[rb][kc], A[rb], 0, 0, 0);
  };

  // ---- tile 0: compute, stats (diag-masked), tau, consume ----
  loadA(0);
  mfma_tile(accA, a);
  loadA2(1);
  bool diag0 = (row_base == col0);
  int cq0 = col0 + w * 16 + q * 4;
  float s1 = 0.f, s2 = 0.f;
#pragma unroll
  for (int rb = 0; rb < 4; ++rb) {
    int myrow = row_base + rb * 16 + c;
#pragma unroll
    for (int r = 0; r < 4; ++r) {
      float v = accA[rb][r];
      v = (diag0 && (cq0 + r == myrow)) ? 0.f : v;
      s1 += v;
      s2 = fmaf(v, v, s2);
    }
  }
#pragma unroll
  for (int off = 1; off < 64; off <<= 1) {
    s1 += __shfl_xor(s1, off);
    s2 += __shfl_xor(s2, off);
  }
  if (l == 0) { sred[0][w] = s1; sred[1][w] = s2; }
  __syncthreads();
  float n = diag0 ? 4032.f : 4096.f;
  float ts1 = sred[0][0] + sred[0][1] + sred[0][2] + sred[0][3];
  float ts2 = sred[1][0] + sred[1][1] + sred[1][2] + sred[1][3];
  float mu = ts1 / n;
  float sig = sqrtf(fmaxf(ts2 / n - mu * mu, 0.f));
  float tau = mu + 2.5f * sig;  // lambda ~13 survivors per row-quarter
  if (threadIdx.x == 0) taug[(dir * 128 + rowg) * 4 + qtr] = tau;
  consume4(accA, cand, lcnt, tau, c);

  // ---- tile 1, then pipelined pairs (2,3)...(30,31) ----
  mfma_tile(accA, a2);
  loadA(2);
  for (int t = 2; t < 32; t += 2) {
    mfma_tile(accB, a);                 // tile t
    loadA2(t + 1);
    consume4(accA, cand, lcnt, tau, c); // tile t-1 (overlaps accB MFMAs)
    mfma_tile(accA, a2);                // tile t+1
    loadA(t + 2);                       // wraps harmlessly at t=30
    consume4(accB, cand, lcnt, tau, c); // tile t
  }
  consume4(accA, cand, lcnt, tau, c);   // tile 31

  // ---- epilogue: per-row top-11, drop max if this qtr holds the diag ----
  __syncthreads();
  if (threadIdx.x < 64) {
    int rl = threadIdx.x;
    int cc = lcnt[rl];
    float t11[11];
#pragma unroll
    for (int j = 0; j < 11; ++j) t11[j] = NEG_INF;
    int m = cc < CAP ? cc : CAP;
    for (int i = 0; i < m; ++i) {
      float v = cand[rl][i];
      if (v > t11[0]) insert11(t11, v);
    }
    bool diagq = (row_base >= col0) && (row_base < col0 + 2048);
    float* o = tk + ((size_t)(dir * NB + row_base + rl) * 4 + qtr) * 10;
    if (diagq) {  // t11[10] is the self-sim (max) -> drop it
#pragma unroll
      for (int j = 0; j < 10; ++j) o[j] = t11[j];
    } else {      // keep the 10 largest
#pragma unroll
      for (int j = 0; j < 10; ++j) o[j] = t11[j + 1];
    }
    cnth[(dir * NB + row_base + rl) * 4 + qtr] = cc;
  }
}

// ---------------------------------------------------------------------------
// Kernel 3: merge 4 quarter-lists, tau-proof, soft-sort + BCE; exact
// brute-force fallback for unproven rows (statistically never fires).
// ---------------------------------------------------------------------------
__global__ __launch_bounds__(64, 1) void ksort(const float* __restrict__ tk,
                                               const float* __restrict__ pos,
                                               const int* __restrict__ cnth,
                                               const float* __restrict__ taug,
                                               const __bf16* __restrict__ an_all,
                                               float* __restrict__ out) {
  int tid = blockIdx.x * 64 + threadIdx.x;
  int dir = tid >> 13;
  int row = tid & (NB - 1);
  int lane = threadIdx.x;

  const float* A = tk + (size_t)(dir * NB + row) * 40;
  float s10[10];
#pragma unroll
  for (int j = 0; j < 10; ++j) s10[j] = A[j];
#pragma unroll
  for (int g = 1; g < 4; ++g)
#pragma unroll
    for (int j = 0; j < 10; ++j) {
      float v = A[g * 10 + j];
      if (v > s10[0]) insert10(s10, v);
    }
  int rowg = row >> 6;
  const float* T = taug + (size_t)(dir * 128 + rowg) * 4;
  float tmax = fmaxf(fmaxf(T[0], T[1]), fmaxf(T[2], T[3]));
  int4 cc = ((const int4*)cnth)[dir * NB + row];
  // Proof: every unreported sim is <= its quarter's tau <= tmax <= s10[0],
  // and no quarter overflowed CAP -> s10 is the exact top-10.
  bool ok = (cc.x <= CAP) && (cc.y <= CAP) && (cc.z <= CAP) && (cc.w <= CAP) &&
            (s10[0] >= tmax);

  float C = 0.f;
  if (ok) {
    float x[11];
#pragma unroll
    for (int j = 0; j < 10; ++j) x[j] = s10[j];
    x[10] = pos[row];
    C = row_loss(x);
  }
#pragma unroll
  for (int off = 1; off < 64; off <<= 1) C += __shfl_xor(C, off);
  if (lane == 0) atomicAdd(out, C * (-1.f / (2.f * (float)NB * 11.f)));

  unsigned long long bad = __ballot(!ok);
  if (bad == 0ull) return;
  __shared__ float rv[128];
  __shared__ float lst[64][10];
  const __bf16* an = an_all + (size_t)dir * NB * ND;
  while (bad) {
    int b = __ffsll((long long)bad) - 1;
    bad &= bad - 1;
    int brow = (blockIdx.x * 64 + b) & (NB - 1);
    bf16x2 pr = ((const bf16x2*)an)[(size_t)brow * 64 + lane];
    rv[lane * 2] = (float)pr[0];
    rv[lane * 2 + 1] = (float)pr[1];
    __syncthreads();
    float t10[10];
#pragma unroll
    for (int j = 0; j < 10; ++j) t10[j] = NEG_INF;
    for (int i = 0; i < 128; ++i) {
      int col = lane + i * 64;
      if (col == brow) continue;
      const bf16x8* cp = (const bf16x8*)(an + (size_t)col * ND);
      float d = 0.f;
#pragma unroll
      for (int k = 0; k < 16; ++k) {
        bf16x8 p = cp[k];
#pragma unroll
        for (int e = 0; e < 8; ++e) d = fmaf(rv[k * 8 + e], (float)p[e], d);
      }
      if (d > t10[0]) insert10(t10, d);
    }
#pragma unroll
    for (int j = 0; j < 10; ++j) lst[lane][j] = t10[j];
    __syncthreads();
    if (lane == 0) {
      float cur[10];
#pragma unroll
      for (int j = 0; j < 10; ++j) cur[j] = lst[0][j];
      for (int s = 1; s < 64; ++s)
        for (int j = 0; j < 10; ++j) {
          float v = lst[s][j];
          if (v > cur[0]) insert10(cur, v);
        }
      float x[11];
#pragma unroll
      for (int j = 0; j < 10; ++j) x[j] = cur[j];
      x[10] = pos[brow];
      atomicAdd(out, row_loss(x) * (-1.f / (2.f * (float)NB * 11.f)));
    }
    __syncthreads();
  }
}

// ---------------------------------------------------------------------------
// ws: [an bf16 4MB][pos 32KB][tk 2.62MB][cnth 256KB][taug 4KB]. 3 nodes, no
// memsets: knorm zeroes d_out; cnth/taug written unconditionally by kgram.
// ---------------------------------------------------------------------------
extern "C" void kernel_launch(void* const* d_in, const int* in_sizes, int n_in,
                              void* d_out, int out_size, void* d_ws, size_t ws_size,
                              hipStream_t stream) {
  const float* aug1 = (const float*)d_in[0];
  const float* aug2 = (const float*)d_in[1];
  char* w = (char*)d_ws;
  __bf16* an = (__bf16*)w;
  float* pos = (float*)(w + (size_t)4 * 1024 * 1024);
  float* tk = pos + NB;
  int* cnth = (int*)(tk + (size_t)2 * NB * 40);
  float* taug = (float*)(cnth + (size_t)2 * NB * 4);

  knorm<<<dim3(NB / 4), dim3(256), 0, stream>>>(aug1, aug2, an, pos, (float*)d_out);
  kgram<<<dim3(512, 2), dim3(256), 0, stream>>>(an, tk, cnth, taug);
  ksort<<<dim3(2 * NB / 64), dim3(64), 0, stream>>>(tk, pos, cnth, taug, an, (float*)d_out);
}

// Round 8
// 148.572 us; speedup vs baseline: 1.0162x; 1.0162x over previous
//
#include <hip/hip_runtime.h>
#include <cstdint>
#include <cmath>

#define NB 8192
#define ND 128
#define CAP 64
#define NEG_INF (-__builtin_inff())

typedef __attribute__((ext_vector_type(8))) __bf16 bf16x8;
typedef __attribute__((ext_vector_type(2))) __bf16 bf16x2;
typedef __attribute__((ext_vector_type(4))) float f32x4;

// Insert v into ascending top-K list (identity when v <= t[0]).
__device__ __forceinline__ void insert10(float t[10], float v) {
#pragma unroll
  for (int j = 0; j < 9; ++j) t[j] = __builtin_amdgcn_fmed3f(t[j], t[j + 1], v);
  t[9] = fmaxf(t[9], v);
}
__device__ __forceinline__ void insert11(float t[11], float v) {
#pragma unroll
  for (int j = 0; j < 10; ++j) t[j] = __builtin_amdgcn_fmed3f(t[j], t[j + 1], v);
  t[10] = fmaxf(t[10], v);
}

// ---------------------------------------------------------------------------
// Row loss via column-10-only soft sort (P row-stochastic => p_neg = 1-p_pos,
// clips no-ops, both BCEs identical). Verified exact R3/R5/R6/R7 (absmax 0).
// ---------------------------------------------------------------------------
__device__ float row_loss(float x[11]) {
  float al[55];
#pragma unroll
  for (int layer = 0; layer < 11; ++layer) {
#pragma unroll
    for (int p = 0; p < 5; ++p) {
      int ii = (layer & 1) + 2 * p;
      float av = x[ii], bv = x[ii + 1];
      float a = atanf(bv - av) * 0.3183098861837907f + 0.5f;
      al[layer * 5 + p] = a;
      float be = 1.f - a;
      x[ii] = a * av + be * bv;
      x[ii + 1] = be * av + a * bv;
    }
  }
  float v[11];
#pragma unroll
  for (int i = 0; i < 11; ++i) v[i] = 0.f;
  v[10] = 1.f;
#pragma unroll
  for (int layer = 10; layer >= 0; --layer) {
#pragma unroll
    for (int p = 0; p < 5; ++p) {
      int ii = (layer & 1) + 2 * p;
      float a = al[layer * 5 + p];
      float be = 1.f - a;
      float va = v[ii], vb = v[ii + 1];
      v[ii] = a * va + be * vb;
      v[ii + 1] = be * va + a * vb;
    }
  }
  float C = fmaxf(logf(v[10]), -100.f);
#pragma unroll
  for (int i = 0; i < 10; ++i) C += fmaxf(logf(1.f - v[i]), -100.f);
  return C;
}

// ---------------------------------------------------------------------------
// Kernel 1: row-normalize -> bf16 + fp32 pos_sims; block 0 zeroes d_out.
// ---------------------------------------------------------------------------
__global__ __launch_bounds__(256, 4) void knorm(const float* __restrict__ aug1,
                                                const float* __restrict__ aug2,
                                                __bf16* __restrict__ an,
                                                float* __restrict__ pos,
                                                float* __restrict__ out) {
  if (blockIdx.x == 0 && threadIdx.x == 0) out[0] = 0.f;
  int wid = threadIdx.x >> 6;
  int l = threadIdx.x & 63;
  int row = blockIdx.x * 4 + wid;
  const float2* a1 = (const float2*)(aug1) + (size_t)row * 64;
  const float2* a2 = (const float2*)(aug2) + (size_t)row * 64;
  float2 v1 = a1[l], v2 = a2[l];
  float ss1 = v1.x * v1.x + v1.y * v1.y;
  float ss2 = v2.x * v2.x + v2.y * v2.y;
  float dp = v1.x * v2.x + v1.y * v2.y;
#pragma unroll
  for (int off = 1; off < 64; off <<= 1) {
    ss1 += __shfl_xor(ss1, off);
    ss2 += __shfl_xor(ss2, off);
    dp += __shfl_xor(dp, off);
  }
  float inv1 = 1.0f / fmaxf(sqrtf(ss1), 1e-8f);
  float inv2 = 1.0f / fmaxf(sqrtf(ss2), 1e-8f);
  bf16x2 o1, o2;
  o1[0] = (__bf16)(v1.x * inv1);
  o1[1] = (__bf16)(v1.y * inv1);
  o2[0] = (__bf16)(v2.x * inv2);
  o2[1] = (__bf16)(v2.y * inv2);
  ((bf16x2*)(an))[(size_t)row * 64 + l] = o1;
  ((bf16x2*)(an + (size_t)NB * ND))[(size_t)row * 64 + l] = o2;
  if (l == 0) pos[row] = dp * inv1 * inv2;
}

// ---------------------------------------------------------------------------
// Kernel 2: fused Gram + threshold filter. Quarter columns per block
// (grid 1024). Survivors go to per-(lane,rb) REGISTER mini-stacks (3 deep,
// cndmask-selected) -- no LDS atomic round-trip in the hot loop (R6/R7's
// ~650 cyc/tile stall). Mini overflow (P~1%/lane-kernel) spills to the LDS
// atomic path (exact). Minis flush to shared cand buffers at kernel end.
// ---------------------------------------------------------------------------
__global__ __launch_bounds__(256, 3) void kgram(const __bf16* __restrict__ an_all,
                                                float* __restrict__ tk,
                                                int* __restrict__ cnth,
                                                float* __restrict__ taug) {
  int dir = blockIdx.y;
  int rowg = blockIdx.x >> 2;
  int qtr = blockIdx.x & 3;
  const bf16x8* an8 = (const bf16x8*)(an_all + (size_t)dir * NB * ND);
  int w = threadIdx.x >> 6;
  int l = threadIdx.x & 63;
  int q = l >> 4;
  int c = l & 15;
  int row_base = rowg * 64;
  const int col0 = qtr * 2048;

  __shared__ float cand[64][CAP];
  __shared__ int lcnt[64];
  __shared__ float sred[2][4];
  if (threadIdx.x < 64) lcnt[threadIdx.x] = 0;

  // Row fragments (B-operand), resident all kernel.
  bf16x8 brow[4][4];
#pragma unroll
  for (int rb = 0; rb < 4; ++rb)
#pragma unroll
    for (int kc = 0; kc < 4; ++kc)
      brow[rb][kc] = an8[(size_t)(row_base + rb * 16 + c) * 16 + kc * 4 + q];

  const bf16x8* pf0 = an8 + ((size_t)(col0 + w * 16 + c) * 16 + q);
  bf16x8 a[4], a2[4];
  const f32x4 zz = {0.f, 0.f, 0.f, 0.f};
  f32x4 acc[4];

  // Register mini-stacks: 3 values + count per row-block.
  float mini[4][3];
  int mcnt[4];
#pragma unroll
  for (int rb = 0; rb < 4; ++rb) {
    mcnt[rb] = 0;
#pragma unroll
    for (int j = 0; j < 3; ++j) mini[rb][j] = NEG_INF;
  }

  auto loadA = [&](int t) {
    const bf16x8* p = pf0 + (size_t)(t & 31) * 1024;
#pragma unroll
    for (int kc = 0; kc < 4; ++kc) a[kc] = p[kc * 4];
  };
  auto loadA2 = [&](int t) {
    const bf16x8* p = pf0 + (size_t)(t & 31) * 1024;
#pragma unroll
    for (int kc = 0; kc < 4; ++kc) a2[kc] = p[kc * 4];
  };
  auto mfma_tile = [&](const bf16x8* src) {
#pragma unroll
    for (int rb = 0; rb < 4; ++rb)
      acc[rb] = __builtin_amdgcn_mfma_f32_16x16x32_bf16(src[0], brow[rb][0], zz, 0, 0, 0);
#pragma unroll
    for (int kc = 1; kc < 4; ++kc)
#pragma unroll
      for (int rb = 0; rb < 4; ++rb)
        acc[rb] = __builtin_amdgcn_mfma_f32_16x16x32_bf16(src[kc], brow[rb][kc], acc[rb], 0, 0, 0);
  };
  auto consume = [&](float tau) {
#pragma unroll
    for (int rb = 0; rb < 4; ++rb) {
#pragma unroll
      for (int r = 0; r < 4; ++r) {
        float v = acc[rb][r];
        if (v > tau) {  // survivors ~0.6% of slots
          int nn = mcnt[rb];
          mini[rb][0] = (nn == 0) ? v : mini[rb][0];
          mini[rb][1] = (nn == 1) ? v : mini[rb][1];
          mini[rb][2] = (nn == 2) ? v : mini[rb][2];
          if (nn >= 3) {  // rare spill: exact, keeps counts truthful
            int s = atomicAdd(&lcnt[rb * 16 + c], 1);
            if (s < CAP) cand[rb * 16 + c][s] = v;
          }
          mcnt[rb] = nn + 1;
        }
      }
    }
  };

  // ---- tile 0: compute, stats (diag-masked), tau, consume ----
  loadA(0);
  mfma_tile(a);
  loadA2(1);  // in flight across the stats reduction
  bool diag0 = (row_base == col0);
  int cq0 = col0 + w * 16 + q * 4;
  float s1 = 0.f, s2 = 0.f;
#pragma unroll
  for (int rb = 0; rb < 4; ++rb) {
    int myrow = row_base + rb * 16 + c;
#pragma unroll
    for (int r = 0; r < 4; ++r) {
      float v = acc[rb][r];
      v = (diag0 && (cq0 + r == myrow)) ? 0.f : v;
      s1 += v;
      s2 = fmaf(v, v, s2);
    }
  }
#pragma unroll
  for (int off = 1; off < 64; off <<= 1) {
    s1 += __shfl_xor(s1, off);
    s2 += __shfl_xor(s2, off);
  }
  if (l == 0) { sred[0][w] = s1; sred[1][w] = s2; }
  __syncthreads();
  float n = diag0 ? 4032.f : 4096.f;
  float ts1 = sred[0][0] + sred[0][1] + sred[0][2] + sred[0][3];
  float ts2 = sred[1][0] + sred[1][1] + sred[1][2] + sred[1][3];
  float mu = ts1 / n;
  float sig = sqrtf(fmaxf(ts2 / n - mu * mu, 0.f));
  float tau = mu + 2.5f * sig;  // lambda ~13 survivors per row-quarter
  if (threadIdx.x == 0) taug[(dir * 128 + rowg) * 4 + qtr] = tau;
  consume(tau);

  // ---- tiles 1..31: a2/a alternate; loads covered by consume+MFMA+TLP ----
  for (int t = 1; t < 31; t += 2) {
    mfma_tile(a2);
    loadA(t + 1);
    consume(tau);  // tile t
    mfma_tile(a);
    loadA2(t + 2);  // t=29 -> loads tile 31
    consume(tau);  // tile t+1
  }
  mfma_tile(a2);
  consume(tau);  // tile 31

  // ---- flush mini-stacks to shared cand (once per kernel) ----
#pragma unroll
  for (int rb = 0; rb < 4; ++rb) {
    int k = mcnt[rb] < 3 ? mcnt[rb] : 3;
    if (k > 0) {
      int rl = rb * 16 + c;
      int s = atomicAdd(&lcnt[rl], k);
#pragma unroll
      for (int j = 0; j < 3; ++j)
        if (j < k && s + j < CAP) cand[rl][s + j] = mini[rb][j];
    }
  }

  // ---- epilogue: per-row top-11, drop max if this qtr holds the diag ----
  __syncthreads();
  if (threadIdx.x < 64) {
    int rl = threadIdx.x;
    int cc = lcnt[rl];
    float t11[11];
#pragma unroll
    for (int j = 0; j < 11; ++j) t11[j] = NEG_INF;
    int m = cc < CAP ? cc : CAP;
    for (int i = 0; i < m; ++i) {
      float v = cand[rl][i];
      if (v > t11[0]) insert11(t11, v);
    }
    bool diagq = (row_base >= col0) && (row_base < col0 + 2048);
    float* o = tk + ((size_t)(dir * NB + row_base + rl) * 4 + qtr) * 10;
    if (diagq) {  // t11[10] is the self-sim (max) -> drop it
#pragma unroll
      for (int j = 0; j < 10; ++j) o[j] = t11[j];
    } else {
#pragma unroll
      for (int j = 0; j < 10; ++j) o[j] = t11[j + 1];
    }
    cnth[(dir * NB + row_base + rl) * 4 + qtr] = cc;
  }
}

// ---------------------------------------------------------------------------
// Kernel 3: merge 4 quarter-lists, tau-proof, soft-sort + BCE; exact
// brute-force fallback for unproven rows (statistically never fires).
// ---------------------------------------------------------------------------
__global__ __launch_bounds__(64, 1) void ksort(const float* __restrict__ tk,
                                               const float* __restrict__ pos,
                                               const int* __restrict__ cnth,
                                               const float* __restrict__ taug,
                                               const __bf16* __restrict__ an_all,
                                               float* __restrict__ out) {
  int tid = blockIdx.x * 64 + threadIdx.x;
  int dir = tid >> 13;
  int row = tid & (NB - 1);
  int lane = threadIdx.x;

  const float* A = tk + (size_t)(dir * NB + row) * 40;
  float s10[10];
#pragma unroll
  for (int j = 0; j < 10; ++j) s10[j] = A[j];
#pragma unroll
  for (int g = 1; g < 4; ++g)
#pragma unroll
    for (int j = 0; j < 10; ++j) {
      float v = A[g * 10 + j];
      if (v > s10[0]) insert10(s10, v);
    }
  int rowg = row >> 6;
  const float* T = taug + (size_t)(dir * 128 + rowg) * 4;
  float tmax = fmaxf(fmaxf(T[0], T[1]), fmaxf(T[2], T[3]));
  int4 cc = ((const int4*)cnth)[dir * NB + row];
  // Proof: every unreported sim is <= its quarter's tau <= tmax <= s10[0],
  // and no quarter overflowed CAP -> s10 is the exact top-10.
  bool ok = (cc.x <= CAP) && (cc.y <= CAP) && (cc.z <= CAP) && (cc.w <= CAP) &&
            (s10[0] >= tmax);

  float C = 0.f;
  if (ok) {
    float x[11];
#pragma unroll
    for (int j = 0; j < 10; ++j) x[j] = s10[j];
    x[10] = pos[row];
    C = row_loss(x);
  }
#pragma unroll
  for (int off = 1; off < 64; off <<= 1) C += __shfl_xor(C, off);
  if (lane == 0) atomicAdd(out, C * (-1.f / (2.f * (float)NB * 11.f)));

  unsigned long long bad = __ballot(!ok);
  if (bad == 0ull) return;
  __shared__ float rv[128];
  __shared__ float lst[64][10];
  const __bf16* an = an_all + (size_t)dir * NB * ND;
  while (bad) {
    int b = __ffsll((long long)bad) - 1;
    bad &= bad - 1;
    int brow = (blockIdx.x * 64 + b) & (NB - 1);
    bf16x2 pr = ((const bf16x2*)an)[(size_t)brow * 64 + lane];
    rv[lane * 2] = (float)pr[0];
    rv[lane * 2 + 1] = (float)pr[1];
    __syncthreads();
    float t10[10];
#pragma unroll
    for (int j = 0; j < 10; ++j) t10[j] = NEG_INF;
    for (int i = 0; i < 128; ++i) {
      int col = lane + i * 64;
      if (col == brow) continue;
      const bf16x8* cp = (const bf16x8*)(an + (size_t)col * ND);
      float d = 0.f;
#pragma unroll
      for (int k = 0; k < 16; ++k) {
        bf16x8 p = cp[k];
#pragma unroll
        for (int e = 0; e < 8; ++e) d = fmaf(rv[k * 8 + e], (float)p[e], d);
      }
      if (d > t10[0]) insert10(t10, d);
    }
#pragma unroll
    for (int j = 0; j < 10; ++j) lst[lane][j] = t10[j];
    __syncthreads();
    if (lane == 0) {
      float cur[10];
#pragma unroll
      for (int j = 0; j < 10; ++j) cur[j] = lst[0][j];
      for (int s = 1; s < 64; ++s)
        for (int j = 0; j < 10; ++j) {
          float v = lst[s][j];
          if (v > cur[0]) insert10(cur, v);
        }
      float x[11];
#pragma unroll
      for (int j = 0; j < 10; ++j) x[j] = cur[j];
      x[10] = pos[brow];
      atomicAdd(out, row_loss(x) * (-1.f / (2.f * (float)NB * 11.f)));
    }
    __syncthreads();
  }
}

// ---------------------------------------------------------------------------
// ws: [an bf16 4MB][pos 32KB][tk 2.62MB][cnth 256KB][taug 4KB]. 3 nodes,
// no memsets.
// ---------------------------------------------------------------------------
extern "C" void kernel_launch(void* const* d_in, const int* in_sizes, int n_in,
                              void* d_out, int out_size, void* d_ws, size_t ws_size,
                              hipStream_t stream) {
  const float* aug1 = (const float*)d_in[0];
  const float* aug2 = (const float*)d_in[1];
  char* w = (char*)d_ws;
  __bf16* an = (__bf16*)w;
  float* pos = (float*)(w + (size_t)4 * 1024 * 1024);
  float* tk = pos + NB;
  int* cnth = (int*)(tk + (size_t)2 * NB * 40);
  float* taug = (float*)(cnth + (size_t)2 * NB * 4);

  knorm<<<dim3(NB / 4), dim3(256), 0, stream>>>(aug1, aug2, an, pos, (float*)d_out);
  kgram<<<dim3(512, 2), dim3(256), 0, stream>>>(an, tk, cnth, taug);
  ksort<<<dim3(2 * NB / 64), dim3(64), 0, stream>>>(tk, pos, cnth, taug, an, (float*)d_out);
}